// Round 2
// baseline (202.219 us; speedup 1.0000x reference)
//
#include <hip/hip_runtime.h>

#define D 64
#define H 16

// One position (b,s) is handled by 16 consecutive threads; each thread
// produces 4 consecutive floats of the 64-wide embedding (float4 store).
// Token path: float4 gather from emb_table. Numeric path: 2-layer MLP on
// the scalar, weights staged in LDS (w2 transposed to [h][d] so the per-j
// ds_read_b128 across the 16 lane-groups spans all 32 banks — the [d][h]
// layout would be a 16-way bank conflict).
__global__ __launch_bounds__(256) void Embedder_kernel(
    const float* __restrict__ input_ids,
    const int*   __restrict__ type_mask,
    const float* __restrict__ emb,
    const float* __restrict__ w1,
    const float* __restrict__ b1,
    const float* __restrict__ w2,
    const float* __restrict__ b2,
    float*       __restrict__ out,
    int npos)
{
    __shared__ float s_w1[H];
    __shared__ float s_b1[H];
    __shared__ float s_b2[D];
    __shared__ float s_w2t[H * D];   // transposed: [j][d]

    const int tid = threadIdx.x;
    if (tid < H) { s_w1[tid] = w1[tid]; s_b1[tid] = b1[tid]; }
    if (tid >= 64 && tid < 64 + D) s_b2[tid - 64] = b2[tid - 64];
    for (int i = tid; i < D * H; i += 256) {
        // source w2 is [d][j] row-major (64 x 16); dest is [j][d]
        int d = i >> 4, j = i & 15;
        s_w2t[j * D + d] = w2[i];
    }
    __syncthreads();

    const int gid = blockIdx.x * 256 + tid;
    const int pos = gid >> 4;             // which (b,s) position
    if (pos >= npos) return;
    const int d4 = (gid & 15) * 4;        // this thread's 4 output dims

    const float x = input_ids[pos];
    const int   m = type_mask[pos];

    float4 r;
    if (m) {
        // token path: embedding gather (table is L2/L3-resident, 8 MB)
        const int id = (int)x;
        r = *reinterpret_cast<const float4*>(&emb[(size_t)id * D + d4]);
    } else {
        // numeric path: h = relu(x*w1 + b1); out = w2 @ h + b2
        float h[H];
        #pragma unroll
        for (int j = 0; j < H; ++j)
            h[j] = fmaxf(fmaf(x, s_w1[j], s_b1[j]), 0.0f);
        float4 acc = *reinterpret_cast<const float4*>(&s_b2[d4]);
        #pragma unroll
        for (int j = 0; j < H; ++j) {
            const float4 w = *reinterpret_cast<const float4*>(&s_w2t[j * D + d4]);
            acc.x = fmaf(h[j], w.x, acc.x);
            acc.y = fmaf(h[j], w.y, acc.y);
            acc.z = fmaf(h[j], w.z, acc.z);
            acc.w = fmaf(h[j], w.w, acc.w);
        }
        r = acc;
    }
    *reinterpret_cast<float4*>(&out[(size_t)pos * D + d4]) = r;
}

extern "C" void kernel_launch(void* const* d_in, const int* in_sizes, int n_in,
                              void* d_out, int out_size, void* d_ws, size_t ws_size,
                              hipStream_t stream) {
    const float* input_ids = (const float*)d_in[0];
    const int*   type_mask = (const int*)d_in[1];
    const float* emb       = (const float*)d_in[2];
    const float* w1        = (const float*)d_in[3];
    const float* b1        = (const float*)d_in[4];
    const float* w2        = (const float*)d_in[5];
    const float* b2        = (const float*)d_in[6];
    float*       out       = (float*)d_out;

    const int npos = in_sizes[0];              // B*S = 524288
    const long long nthreads = (long long)npos * 16;
    const int blocks = (int)((nthreads + 255) / 256);

    Embedder_kernel<<<blocks, 256, 0, stream>>>(
        input_ids, type_mask, emb, w1, b1, w2, b2, out, npos);
}

// Round 4
// 184.486 us; speedup vs baseline: 1.0961x; 1.0961x over previous
//
#include <hip/hip_runtime.h>

#define D 64
#define H 16
#define PPT 16   // positions per thread (grid-stride slots)

typedef float f32x4 __attribute__((ext_vector_type(4)));

// Slot layout: slot = pos*16 + lane16; each slot produces 4 consecutive
// floats (f32x4) of the 64-wide output. Each thread owns a FIXED d4 slice
// across all its PPT positions, so the w2 rows d4..d4+3 (64 floats), w1/b1
// (32 floats) and the b2 slice live in REGISTERS — zero LDS in the kernel
// (round-2 rocprof showed the DS pipe saturated at ~180k cyc/CU from the
// per-position w2 reads; that WAS the 79 us). Branchless: gather + MLP both
// computed, select. Nontemporal stores keep the 134 MB output stream from
// evicting the 8 MB emb_table out of L2.
__global__ __launch_bounds__(256, 3) void Embedder_kernel(
    const float* __restrict__ input_ids,
    const int*   __restrict__ type_mask,
    const float* __restrict__ emb,
    const float* __restrict__ w1,
    const float* __restrict__ b1,
    const float* __restrict__ w2,
    const float* __restrict__ b2,
    float*       __restrict__ out,
    int npos)
{
    const int tid = threadIdx.x;
    const int gid = blockIdx.x * 256 + tid;
    const int T   = (npos * 16) / PPT;     // total threads
    if (gid >= T) return;

    const int d4 = (gid & 15) * 4;         // fixed output-dim slice

    // ---- stage weights into registers (all indices static => VGPRs) ----
    float w2s[4][H];                       // w2s[r][j] = w2[(d4+r)*H + j]
    #pragma unroll
    for (int r = 0; r < 4; ++r) {
        #pragma unroll
        for (int c = 0; c < 4; ++c) {
            const f32x4 t = *reinterpret_cast<const f32x4*>(&w2[(d4 + r) * H + 4 * c]);
            w2s[r][4*c+0] = t.x; w2s[r][4*c+1] = t.y;
            w2s[r][4*c+2] = t.z; w2s[r][4*c+3] = t.w;
        }
    }
    float w1r[H], b1r[H];
    #pragma unroll
    for (int c = 0; c < 4; ++c) {
        const f32x4 tw = *reinterpret_cast<const f32x4*>(&w1[4*c]);
        const f32x4 tb = *reinterpret_cast<const f32x4*>(&b1[4*c]);
        w1r[4*c+0] = tw.x; w1r[4*c+1] = tw.y; w1r[4*c+2] = tw.z; w1r[4*c+3] = tw.w;
        b1r[4*c+0] = tb.x; b1r[4*c+1] = tb.y; b1r[4*c+2] = tb.z; b1r[4*c+3] = tb.w;
    }
    const f32x4 b2s = *reinterpret_cast<const f32x4*>(&b2[d4]);

    const int pbase = gid >> 4;
    const int pstep = T >> 4;              // position stride between iters

    #pragma unroll 1
    for (int k = 0; k < PPT; k += 2) {
        const int p0 = pbase + k * pstep;
        const int p1 = p0 + pstep;

        const float x0 = input_ids[p0];
        const float x1 = input_ids[p1];
        const int   m0 = type_mask[p0];
        const int   m1 = type_mask[p1];

        const int id0 = m0 ? (int)x0 : 0;  // row 0 is the zero PAD row
        const int id1 = m1 ? (int)x1 : 0;
        const f32x4 g0 = *reinterpret_cast<const f32x4*>(&emb[(size_t)id0 * D + d4]);
        const f32x4 g1 = *reinterpret_cast<const f32x4*>(&emb[(size_t)id1 * D + d4]);

        // MLP for both positions (acc = b2; j-ascending fmaf chain)
        f32x4 a0 = b2s, a1 = b2s;
        #pragma unroll
        for (int j = 0; j < H; ++j) {
            const float h0 = fmaxf(fmaf(x0, w1r[j], b1r[j]), 0.0f);
            const float h1 = fmaxf(fmaf(x1, w1r[j], b1r[j]), 0.0f);
            a0.x = fmaf(h0, w2s[0][j], a0.x);  a1.x = fmaf(h1, w2s[0][j], a1.x);
            a0.y = fmaf(h0, w2s[1][j], a0.y);  a1.y = fmaf(h1, w2s[1][j], a1.y);
            a0.z = fmaf(h0, w2s[2][j], a0.z);  a1.z = fmaf(h1, w2s[2][j], a1.z);
            a0.w = fmaf(h0, w2s[3][j], a0.w);  a1.w = fmaf(h1, w2s[3][j], a1.w);
        }

        f32x4 r0, r1;
        r0.x = m0 ? g0.x : a0.x;  r0.y = m0 ? g0.y : a0.y;
        r0.z = m0 ? g0.z : a0.z;  r0.w = m0 ? g0.w : a0.w;
        r1.x = m1 ? g1.x : a1.x;  r1.y = m1 ? g1.y : a1.y;
        r1.z = m1 ? g1.z : a1.z;  r1.w = m1 ? g1.w : a1.w;

        __builtin_nontemporal_store(r0, reinterpret_cast<f32x4*>(&out[(size_t)p0 * D + d4]));
        __builtin_nontemporal_store(r1, reinterpret_cast<f32x4*>(&out[(size_t)p1 * D + d4]));
    }
}

extern "C" void kernel_launch(void* const* d_in, const int* in_sizes, int n_in,
                              void* d_out, int out_size, void* d_ws, size_t ws_size,
                              hipStream_t stream) {
    const float* input_ids = (const float*)d_in[0];
    const int*   type_mask = (const int*)d_in[1];
    const float* emb       = (const float*)d_in[2];
    const float* w1        = (const float*)d_in[3];
    const float* b1        = (const float*)d_in[4];
    const float* w2        = (const float*)d_in[5];
    const float* b2        = (const float*)d_in[6];
    float*       out       = (float*)d_out;

    const int npos = in_sizes[0];                  // B*S = 524288
    const long long T = (long long)npos * 16 / PPT;
    const int blocks = (int)((T + 255) / 256);

    Embedder_kernel<<<blocks, 256, 0, stream>>>(
        input_ids, type_mask, emb, w1, b1, w2, b2, out, npos);
}

// Round 5
// 181.354 us; speedup vs baseline: 1.1150x; 1.0173x over previous
//
#include <hip/hip_runtime.h>

#define D 64
#define H 16
#define PPT 8   // positions per thread, fully unrolled (batch-issue all memory)

typedef float f32x4 __attribute__((ext_vector_type(4)));

// Slot layout: 16 consecutive threads = one position; each thread owns a fixed
// 4-float slice d4 of the 64-wide output (perfect float4 coalescing: a wave
// covers 4 consecutive positions = 1 KB contiguous stores). Weights live in
// registers (round 2 showed the DS pipe was the 79 us wall). Round-5 change:
// PPT halved to 8 and the position loop FULLY unrolled — all 16 input loads
// issue first, then all 8 gathers, then 8x MLP+select+store. This gives ~24
// outstanding VMEM ops per wave (was ~6 with the unroll-1 loop, whose
// register reuse also forced per-iteration store-retire waits). Plain stores
// (not nontemporal): the harness fill kernel proves plain stores hit 82% of
// HBM peak; NT throughput is unproven on gfx950.
__global__ __launch_bounds__(256) void Embedder_kernel(
    const float* __restrict__ input_ids,
    const int*   __restrict__ type_mask,
    const float* __restrict__ emb,
    const float* __restrict__ w1,
    const float* __restrict__ b1,
    const float* __restrict__ w2,
    const float* __restrict__ b2,
    float*       __restrict__ out,
    int npos)
{
    const int tid = threadIdx.x;
    const int gid = blockIdx.x * 256 + tid;
    const int d4 = (gid & 15) * 4;        // fixed output-dim slice
    const int pbase = gid >> 4;           // first position slot
    const int pstep = npos / PPT;         // stride between this thread's positions

    // ---- issue ALL input loads first (longest dep chain: x -> gather) ----
    float xv[PPT]; int mv[PPT];
    #pragma unroll
    for (int k = 0; k < PPT; ++k) {
        const int p = pbase + k * pstep;
        xv[k] = input_ids[p];
        mv[k] = type_mask[p];
    }

    // ---- weight staging into registers (independent; overlaps the above) ----
    float w2s[4][H];                      // w2s[r][j] = w2[(d4+r)*H + j]
    #pragma unroll
    for (int r = 0; r < 4; ++r) {
        #pragma unroll
        for (int c = 0; c < 4; ++c) {
            const f32x4 t = *reinterpret_cast<const f32x4*>(&w2[(d4 + r) * H + 4 * c]);
            w2s[r][4*c+0] = t.x; w2s[r][4*c+1] = t.y;
            w2s[r][4*c+2] = t.z; w2s[r][4*c+3] = t.w;
        }
    }
    float w1r[H], b1r[H];
    #pragma unroll
    for (int c = 0; c < 4; ++c) {
        const f32x4 tw = *reinterpret_cast<const f32x4*>(&w1[4*c]);
        const f32x4 tb = *reinterpret_cast<const f32x4*>(&b1[4*c]);
        w1r[4*c+0] = tw.x; w1r[4*c+1] = tw.y; w1r[4*c+2] = tw.z; w1r[4*c+3] = tw.w;
        b1r[4*c+0] = tb.x; b1r[4*c+1] = tb.y; b1r[4*c+2] = tb.z; b1r[4*c+3] = tb.w;
    }
    const f32x4 b2s = *reinterpret_cast<const f32x4*>(&b2[d4]);

    // ---- all gathers (issue as each xv arrives; stay in flight under MLP) ----
    f32x4 g[PPT];
    #pragma unroll
    for (int k = 0; k < PPT; ++k) {
        const int id = mv[k] ? (int)xv[k] : 0;   // row 0 is the zero PAD row
        g[k] = *reinterpret_cast<const f32x4*>(&emb[(size_t)id * D + d4]);
    }

    // ---- MLP + select + store per position ----
    #pragma unroll
    for (int k = 0; k < PPT; ++k) {
        f32x4 a = b2s;
        #pragma unroll
        for (int j = 0; j < H; ++j) {
            const float h = fmaxf(fmaf(xv[k], w1r[j], b1r[j]), 0.0f);
            a.x = fmaf(h, w2s[0][j], a.x);
            a.y = fmaf(h, w2s[1][j], a.y);
            a.z = fmaf(h, w2s[2][j], a.z);
            a.w = fmaf(h, w2s[3][j], a.w);
        }
        f32x4 r;
        r.x = mv[k] ? g[k].x : a.x;
        r.y = mv[k] ? g[k].y : a.y;
        r.z = mv[k] ? g[k].z : a.z;
        r.w = mv[k] ? g[k].w : a.w;
        *reinterpret_cast<f32x4*>(&out[(size_t)(pbase + k * pstep) * D + d4]) = r;
    }
}

extern "C" void kernel_launch(void* const* d_in, const int* in_sizes, int n_in,
                              void* d_out, int out_size, void* d_ws, size_t ws_size,
                              hipStream_t stream) {
    const float* input_ids = (const float*)d_in[0];
    const int*   type_mask = (const int*)d_in[1];
    const float* emb       = (const float*)d_in[2];
    const float* w1        = (const float*)d_in[3];
    const float* b1        = (const float*)d_in[4];
    const float* w2        = (const float*)d_in[5];
    const float* b2        = (const float*)d_in[6];
    float*       out       = (float*)d_out;

    const int npos = in_sizes[0];                   // B*S = 524288
    const long long T = (long long)npos * 16 / PPT; // 1,048,576 threads
    const int blocks = (int)((T + 255) / 256);      // 4096 blocks

    Embedder_kernel<<<blocks, 256, 0, stream>>>(
        input_ids, type_mask, emb, w1, b1, w2, b2, out, npos);
}